// Round 1
// 604.245 us; speedup vs baseline: 1.1764x; 1.1764x over previous
//
#include <hip/hip_runtime.h>
#include <hip/hip_bf16.h>
#include <stdint.h>

// Problem constants (fixed by the reference setup)
#define NROWS 8192   // N (batch rows of x)
#define IN_F  4096   // K
#define OUT_F 4096   // N (output features)
#define RANK  16
#define SCALE 0.0025f  // SIGMA / sqrt(r) * SIGN = 0.01 / 4 * 1.0

typedef __bf16 bf16x8 __attribute__((ext_vector_type(8)));
typedef float f32x4 __attribute__((ext_vector_type(4)));
typedef float f32x16 __attribute__((ext_vector_type(16)));

// ---------------------------------------------------------------------------
// Kernel 1: Pbt[r][i] = sum_j P[i][j] * noise[j][r]   (Pb = P @ b_mat, stored
// transposed 16 x 4096). 4 P-rows per block: each block reads all of b_mat
// (256 KB, L2-resident) once, so G=4 cuts that L2 stream 1 GB -> 256 MB.
// Per-thread j-partition identical to the G=1 version (bitwise-same sums).
// ---------------------------------------------------------------------------
__global__ __launch_bounds__(256) void pb_kernel(const float* __restrict__ P,
                                                 const float* __restrict__ noise,
                                                 float* __restrict__ Pbt) {
  int i0 = blockIdx.x * 4;
  int tid = threadIdx.x;
  int lane = tid & 63;
  int wave = tid >> 6;
  float acc[4][RANK];
#pragma unroll
  for (int nn = 0; nn < 4; ++nn)
#pragma unroll
    for (int r = 0; r < RANK; ++r) acc[nn][r] = 0.f;
  const float* P0 = P + (size_t)i0 * IN_F;
  for (int j = tid; j < IN_F; j += 256) {
    const f32x4* brow = (const f32x4*)(noise + (size_t)j * RANK);
    f32x4 b0 = brow[0], b1 = brow[1], b2 = brow[2], b3 = brow[3];
#pragma unroll
    for (int nn = 0; nn < 4; ++nn) {
      float p = P0[(size_t)nn * IN_F + j];
#pragma unroll
      for (int q = 0; q < 4; ++q) {
        acc[nn][q] += p * b0[q];
        acc[nn][4 + q] += p * b1[q];
        acc[nn][8 + q] += p * b2[q];
        acc[nn][12 + q] += p * b3[q];
      }
    }
  }
  // wave reduce (64 lanes)
#pragma unroll
  for (int off = 32; off > 0; off >>= 1)
#pragma unroll
    for (int nn = 0; nn < 4; ++nn)
#pragma unroll
      for (int r = 0; r < RANK; ++r) acc[nn][r] += __shfl_down(acc[nn][r], off, 64);
  __shared__ float red[4][4][RANK];
  if (lane == 0)
#pragma unroll
    for (int nn = 0; nn < 4; ++nn)
#pragma unroll
      for (int r = 0; r < RANK; ++r) red[wave][nn][r] = acc[nn][r];
  __syncthreads();
  if (tid < 4 * RANK) {
    int nn = tid >> 4, r = tid & 15;
    float s = red[0][nn][r] + red[1][nn][r] + red[2][nn][r] + red[3][nn][r];
    Pbt[(size_t)r * IN_F + i0 + nn] = s;
  }
}

// ---------------------------------------------------------------------------
// Kernel 2: Wb[n][k] = bf16( W[n][k] + SCALE * sum_r a_mat[n][r] * Pbt[r][k] )
// 4 W-rows per block: Pbt (256 KB) is read once per block instead of once per
// row -> L2 stream 1 GB -> 256 MB. ~100 VGPR, still streaming-friendly.
// ---------------------------------------------------------------------------
__global__ __launch_bounds__(256) void wprep_kernel(const float* __restrict__ W,
                                                    const float* __restrict__ noise,
                                                    const float* __restrict__ Pbt,
                                                    __bf16* __restrict__ Wb) {
  int n0 = blockIdx.x * 4;
  int tid = threadIdx.x;
  __shared__ float arow[4][RANK];
  if (tid < 4 * RANK) {
    int nn = tid >> 4, r = tid & 15;
    arow[nn][r] = SCALE * noise[(size_t)(IN_F + n0 + nn) * RANK + r];
  }
  __syncthreads();
  int k0 = tid * 16;
  f32x4 o[4][4];
#pragma unroll
  for (int nn = 0; nn < 4; ++nn) {
    const f32x4* wr = (const f32x4*)(W + (size_t)(n0 + nn) * IN_F + k0);
#pragma unroll
    for (int q = 0; q < 4; ++q) o[nn][q] = wr[q];
  }
#pragma unroll
  for (int r = 0; r < RANK; ++r) {
    const f32x4* pr = (const f32x4*)(Pbt + (size_t)r * IN_F + k0);
    f32x4 p0 = pr[0], p1 = pr[1], p2 = pr[2], p3 = pr[3];
#pragma unroll
    for (int nn = 0; nn < 4; ++nn) {
      float ar = arow[nn][r];
#pragma unroll
      for (int q = 0; q < 4; ++q) {
        o[nn][0][q] += ar * p0[q];
        o[nn][1][q] += ar * p1[q];
        o[nn][2][q] += ar * p2[q];
        o[nn][3][q] += ar * p3[q];
      }
    }
  }
#pragma unroll
  for (int nn = 0; nn < 4; ++nn) {
    __align__(16) __bf16 ob[16];
#pragma unroll
    for (int q = 0; q < 4; ++q)
#pragma unroll
      for (int e = 0; e < 4; ++e) ob[q * 4 + e] = (__bf16)o[nn][q][e];
    *(uint4*)(Wb + (size_t)(n0 + nn) * IN_F + k0) = *(uint4*)&ob[0];
    *(uint4*)(Wb + (size_t)(n0 + nn) * IN_F + k0 + 8) = *(uint4*)&ob[8];
  }
}

// ---------------------------------------------------------------------------
// Kernel 3: cast x (f32) -> bf16   (unchanged; already ~BW-bound)
// ---------------------------------------------------------------------------
__global__ __launch_bounds__(256) void xcast_kernel(const float* __restrict__ X,
                                                    __bf16* __restrict__ Xb) {
  size_t idx = ((size_t)blockIdx.x * 256 + threadIdx.x) * 8;
  f32x4 a = *(const f32x4*)(X + idx);
  f32x4 b = *(const f32x4*)(X + idx + 4);
  __align__(16) __bf16 ob[8];
#pragma unroll
  for (int q = 0; q < 4; q++) {
    ob[q] = (__bf16)a[q];
    ob[4 + q] = (__bf16)b[q];
  }
  *(uint4*)(Xb + idx) = *(uint4*)&ob[0];
}

// ---------------------------------------------------------------------------
// Kernel 4: main GEMM  C[m][n] = sum_k A[m][k]*B[n][k] + bias[n]
//
// NEW STRUCTURE (replaces the m97-style 128x128 / __syncthreads loop that
// ceilinged at ~917 TF, MfmaUtil 42%):
//   256x256 tile, BK=32, 512 threads = 8 waves (2M x 4N), per-wave 128x64
//   as 4x2 frags of v_mfma_f32_32x32x16_bf16.
//   QUAD-buffered LDS (4 x 32 KB = 128 KB), depth-3 prefetch with COUNTED
//   vmcnt (T4) + raw s_barrier -- the main-loop wait is vmcnt(10), never 0,
//   so global_load_lds stays in flight across barriers.
//
// Sync ledger (race-freedom):
//   - tile t lives in buf[t&3]; tile t+3 -> buf[(t+3)&3] != buf[t&3],
//     != buf[(t+2)&3] (mod-4 distinct), so in-flight stages never touch the
//     buffer being read.
//   - barrier A (loop top): all waves finished compute of t-1 => safe to
//     overwrite buf[(t+3)&3] (== buf[(t-1)&3]).
//   - per-wave VMEM issue order is [A2(tile),B2(tile)] groups of 4; at the
//     wait point the newest 10 = A2(t+3)+B2(t+2)+A2(t+2)+B2(t+1)+A2(t+1),
//     so s_waitcnt vmcnt(10) + barrier B => ALL waves' tile-t loads landed.
//   - tail (no staging): vmcnt(8)/(4)/(0) for tiles NT-3/NT-2/NT-1.
//
// LDS swizzle (conflict-free by construction): 16B-block b of row r is
// stored at slot p=(b+(r>>1))&3 within the row's 64 B. global_load_lds
// writes linearly (rule: swizzle BOTH sides via pre-swizzled global source),
// so the staging lane fetches global block (p-(r>>1))&3. Fragment reads use
// p=(c+(l31>>1))&3: 8 consecutive lanes hit all 8 16B bank-slots => exactly
// 4 lanes/bank (the wave64 minimum).
// ---------------------------------------------------------------------------
__global__ __launch_bounds__(512, 2) void gemm_kernel(const __bf16* __restrict__ A,
                                                      const __bf16* __restrict__ B,
                                                      const float* __restrict__ bias,
                                                      float* __restrict__ C) {
  constexpr int K = IN_F;
  constexpr int N = OUT_F;
  constexpr int BK = 32;
  constexpr int NT = K / BK;      // 128
  constexpr int ABUF = 256 * BK;  // 8192 elements = 16 KB (one A or B tile)
  constexpr int BUFE = 2 * ABUF;  // one (A,B) buffer pair
  __shared__ __align__(16) __bf16 sh[4 * BUFE];  // 128 KiB

  const int tid = threadIdx.x;
  const int wave = tid >> 6;
  const int lane = tid & 63;
  const int l31 = lane & 31;
  const int lhi = lane >> 5;
  const int q2 = l31 >> 1;

  // XCD-aware swizzle: blocks with bid%8==x (-> XCD x) get a contiguous
  // 64-wg chunk (4 M-rows x 16 N-cols) for L2 locality. 512%8==0 bijective.
  int bid = blockIdx.x;
  int wg = (bid & 7) * 64 + (bid >> 3);
  int by = wg >> 4;  // 0..31
  int bx = wg & 15;  // 0..15
  const int m0 = by * 256;
  const int n0 = bx * 256;

  const int wm = (wave >> 2) * 128;  // 0 or 128
  const int wn = (wave & 3) * 64;    // 0,64,128,192

  const __bf16* Ab = A + (size_t)m0 * K;
  const __bf16* Bb = B + (size_t)n0 * K;

  // Staging: one wave-issue = 64 lanes x 16 B = 1 KB = 16 rows of 64 B.
  // Thread covers row (s*128 + tid>>2), LDS slot p = tid&3; it must fetch
  // global 16B-block (p - (row>>1))&3; (row>>1)&3 == (tid>>3)&3 for both s.
  const int srow = tid >> 2;
  const int sblk = ((tid & 3) - ((tid >> 3) & 3)) & 3;
  const int scol = sblk * 8;       // element col within BK
  const int ldsw = wave * 512;     // elements: wave chunk within an 8 KB half

  f32x16 acc[4][2];
#pragma unroll
  for (int i = 0; i < 4; ++i)
#pragma unroll
    for (int j = 0; j < 2; ++j) acc[i][j] = (f32x16)(0.f);

  // fragment-read address precompute (all static indexing downstream)
  int rowA[4], rowB[2];
#pragma unroll
  for (int mf = 0; mf < 4; ++mf) rowA[mf] = (wm + mf * 32 + l31) * BK;
#pragma unroll
  for (int nf = 0; nf < 2; ++nf) rowB[nf] = (wn + nf * 32 + l31) * BK;
  // block c = ks*2 + lhi ; slot p = (c + (r>>1))&3, (r>>1)&3 == (l31>>1)&3
  const int po0 = ((lhi + q2) & 3) * 8;      // ks = 0
  const int po1 = ((2 + lhi + q2) & 3) * 8;  // ks = 1

  auto stageA = [&](int tt, int bb) {
#pragma unroll
    for (int s = 0; s < 2; ++s) {
      const __bf16* g = Ab + (size_t)(s * 128 + srow) * K + tt * BK + scol;
      __builtin_amdgcn_global_load_lds(
          (__attribute__((address_space(1))) void*)g,
          (__attribute__((address_space(3))) void*)(sh + bb * BUFE + s * 4096 + ldsw),
          16, 0, 0);
    }
  };
  auto stageB = [&](int tt, int bb) {
#pragma unroll
    for (int s = 0; s < 2; ++s) {
      const __bf16* g = Bb + (size_t)(s * 128 + srow) * K + tt * BK + scol;
      __builtin_amdgcn_global_load_lds(
          (__attribute__((address_space(1))) void*)g,
          (__attribute__((address_space(3))) void*)(sh + bb * BUFE + ABUF + s * 4096 + ldsw),
          16, 0, 0);
    }
  };

  auto do_ks = [&](const __bf16* sa, const __bf16* sbv, int po) {
    bf16x8 af[4], bfr[2];
#pragma unroll
    for (int mf = 0; mf < 4; ++mf) af[mf] = *(const bf16x8*)(sa + rowA[mf] + po);
#pragma unroll
    for (int nf = 0; nf < 2; ++nf) bfr[nf] = *(const bf16x8*)(sbv + rowB[nf] + po);
    __builtin_amdgcn_s_setprio(1);
#pragma unroll
    for (int mf = 0; mf < 4; ++mf)
#pragma unroll
      for (int nf = 0; nf < 2; ++nf)
        acc[mf][nf] = __builtin_amdgcn_mfma_f32_32x32x16_bf16(af[mf], bfr[nf], acc[mf][nf], 0, 0, 0);
    __builtin_amdgcn_s_setprio(0);
  };

  // prologue: tiles 0,1,2 (issue order = groups of 4: [A2,B2] per tile)
  stageA(0, 0); stageB(0, 0);
  stageA(1, 1); stageB(1, 1);
  stageA(2, 2); stageB(2, 2);

#pragma unroll 2
  for (int t = 0; t < NT - 3; ++t) {
    const int bb = t & 3;
    const int nb = (t + 3) & 3;
    __builtin_amdgcn_s_barrier();  // A: all waves done reading tile t-1
    stageA(t + 3, nb);
    asm volatile("s_waitcnt vmcnt(10)" ::: "memory");  // tile t landed (per-wave)
    __builtin_amdgcn_s_barrier();  // B: tile t landed for ALL waves
    const __bf16* sa = sh + bb * BUFE;
    const __bf16* sbv = sa + ABUF;
    do_ks(sa, sbv, po0);
    stageB(t + 3, nb);  // writes buf[nb] != buf[bb]; all waves past barrier B
    do_ks(sa, sbv, po1);
  }
  // tail: tiles NT-3, NT-2, NT-1 (no staging; drain 8 -> 4 -> 0)
  {
    const __bf16* sa = sh + ((NT - 3) & 3) * BUFE;
    asm volatile("s_waitcnt vmcnt(8)" ::: "memory");
    __builtin_amdgcn_s_barrier();
    do_ks(sa, sa + ABUF, po0);
    do_ks(sa, sa + ABUF, po1);
  }
  {
    const __bf16* sa = sh + ((NT - 2) & 3) * BUFE;
    asm volatile("s_waitcnt vmcnt(4)" ::: "memory");
    __builtin_amdgcn_s_barrier();
    do_ks(sa, sa + ABUF, po0);
    do_ks(sa, sa + ABUF, po1);
  }
  {
    const __bf16* sa = sh + ((NT - 1) & 3) * BUFE;
    asm volatile("s_waitcnt vmcnt(0)" ::: "memory");
    __builtin_amdgcn_s_barrier();
    do_ks(sa, sa + ABUF, po0);
    do_ks(sa, sa + ABUF, po1);
  }

  // Epilogue: 32x32 C/D layout col = lane&31,
  // row = (reg&3) + 8*(reg>>2) + 4*(lane>>5)   [m74/m101]
  const int cn = l31;
  const int rb = 4 * lhi;
#pragma unroll
  for (int nf = 0; nf < 2; ++nf) {
    int col = n0 + wn + nf * 32 + cn;
    float bv = bias[col];
#pragma unroll
    for (int mf = 0; mf < 4; ++mf) {
      int rowb = m0 + wm + mf * 32 + rb;
#pragma unroll
      for (int reg = 0; reg < 16; ++reg) {
        int row = rowb + (reg & 3) + 8 * (reg >> 2);
        C[(size_t)row * N + col] = acc[mf][nf][reg] + bv;
      }
    }
  }
}

// ---------------------------------------------------------------------------
extern "C" void kernel_launch(void* const* d_in, const int* in_sizes, int n_in,
                              void* d_out, int out_size, void* d_ws, size_t ws_size,
                              hipStream_t stream) {
  const float* x = (const float*)d_in[0];       // 8192 x 4096
  const float* weight = (const float*)d_in[1];  // 4096 x 4096
  const float* bias = (const float*)d_in[2];    // 4096
  const float* noise = (const float*)d_in[3];   // 8192 x 16
  const float* P = (const float*)d_in[4];       // 4096 x 4096
  float* out = (float*)d_out;                   // 8192 x 4096

  char* ws = (char*)d_ws;
  __bf16* Xb = (__bf16*)ws;                                   // 64 MB
  __bf16* Wb = (__bf16*)(ws + (size_t)NROWS * IN_F * 2);      // 32 MB
  float* Pbt = (float*)(ws + (size_t)NROWS * IN_F * 2 + (size_t)OUT_F * IN_F * 2);  // 256 KB

  pb_kernel<<<IN_F / 4, 256, 0, stream>>>(P, noise, Pbt);
  wprep_kernel<<<OUT_F / 4, 256, 0, stream>>>(weight, noise, Pbt, Wb);
  xcast_kernel<<<(int)(((size_t)NROWS * IN_F) / (8 * 256)), 256, 0, stream>>>(x, Xb);
  gemm_kernel<<<dim3(512), 512, 0, stream>>>(Xb, Wb, bias, out);
}